// Round 4
// baseline (458.711 us; speedup 1.0000x reference)
//
#include <hip/hip_runtime.h>
#include <math.h>

typedef unsigned int u32;
typedef unsigned short u16;
typedef unsigned long long u64;
typedef __attribute__((ext_vector_type(8))) __bf16 bf8;
typedef __attribute__((ext_vector_type(4))) float f4;

#define MFMA(a,b,c) __builtin_amdgcn_mfma_f32_16x16x32_bf16(a,b,c,0,0,0)

static __device__ __forceinline__ u32 cvtpk(float lo, float hi) {
  u32 r; asm("v_cvt_pk_bf16_f32 %0, %1, %2" : "=v"(r) : "v"(lo), "v"(hi));
  return r;
}
static __device__ __forceinline__ u16 f2b(float x) { return (u16)cvtpk(x, 0.f); }
static __device__ __forceinline__ float sigm(float x) { return 1.f/(1.f+__expf(-x)); }

// ---------------- weight transforms (bf16, once per call) ----------------
__global__ __launch_bounds__(256) void k_cvt(const float* __restrict__ in,
        u16* __restrict__ out, int n) {
  int i = blockIdx.x*256 + threadIdx.x;
  if (i < n) out[i] = f2b(in[i]);
}
// conv weight [256][256*9] -> tap-major [9][256][256], 3 kinds in one launch
__global__ __launch_bounds__(256) void k_wt3(const float* __restrict__ wq,
        const float* __restrict__ wk, const float* __restrict__ wv,
        u16* __restrict__ tq, u16* __restrict__ tk, u16* __restrict__ tv) {
  const float* w = (blockIdx.y==0)?wq:(blockIdx.y==1)?wk:wv;
  u16* wt = (blockIdx.y==0)?tq:(blockIdx.y==1)?tk:tv;
  int i = blockIdx.x*256 + threadIdx.x;          // over [9][256][256]
  int tap = i >> 16, mm = (i & 65535) >> 8, rr = i & 255;
  wt[i] = f2b(w[(size_t)mm*2304 + rr*9 + tap]);
}
// gates: [3 gates i,g,o][256 rows][512 k] (k<256: w_ga, else w_gx); skip f-gate
__global__ __launch_bounds__(256) void k_wtg(const float* __restrict__ w_ga,
        const float* __restrict__ w_gx, u16* __restrict__ wg) {
  int i = blockIdx.x*256 + threadIdx.x;          // over [3][256][512]
  int g = i >> 17, rem = i & 131071, rr = rem >> 9, kk = rem & 511;
  int gb = (g == 0) ? 0 : (g == 1) ? 512 : 768;
  float v = (kk < 256) ? w_ga[(size_t)(gb+rr)*256 + kk]
                       : w_gx[(size_t)(gb+rr)*256 + kk - 256];
  wg[i] = f2b(v);
}

// ---------------- xin GEMM: M=256,K=128 over x fp32 ----------------
__global__ __launch_bounds__(256,2) void k_xin(const float* __restrict__ x,
        const u16* __restrict__ wb, const float* __restrict__ bias,
        u16* __restrict__ out) {
  __shared__ u16 Xs[128][40];
  __shared__ u16 Ws[128][40];
  int tid = threadIdx.x, lane = tid & 63, wid = tid >> 6;
  int p0 = blockIdx.x*128, m0 = blockIdx.y*128, n = blockIdx.z;
  int pcol = tid & 127, rg = tid >> 7;
  int p = p0 + pcol;
  const float* src = x + (size_t)n*128*1296;
  f4 z = {0.f,0.f,0.f,0.f};
  f4 acc[4][4];
  #pragma unroll
  for (int i=0;i<4;i++) { acc[i][0]=z; acc[i][1]=z; acc[i][2]=z; acc[i][3]=z; }
  int wm = (wid & 1)*64, wp = (wid >> 1)*64;
  for (int k0 = 0; k0 < 128; k0 += 32) {
    #pragma unroll
    for (int it = 0; it < 8; it++) {
      int rp = it*2 + rg, rr = k0 + rp*2;
      float a = 0.f, b = 0.f;
      if (p < 1296) { a = src[(size_t)rr*1296+p]; b = src[(size_t)(rr+1)*1296+p]; }
      ((u32*)&Xs[pcol][0])[rp] = cvtpk(a, b);
    }
    #pragma unroll
    for (int j2 = 0; j2 < 8; j2++) {
      int idx = tid + j2*256, mm = idx >> 4, rc = idx & 15;
      ((u32*)&Ws[mm][0])[rc] = *(const u32*)&wb[(size_t)(m0+mm)*128 + k0 + rc*2];
    }
    __syncthreads();
    bf8 af[4], bx[4];
    #pragma unroll
    for (int mt=0;mt<4;mt++) af[mt] = *(bf8*)&Ws[wm + mt*16 + (lane&15)][8*(lane>>4)];
    #pragma unroll
    for (int pt=0;pt<4;pt++) bx[pt] = *(bf8*)&Xs[wp + pt*16 + (lane&15)][8*(lane>>4)];
    #pragma unroll
    for (int mt=0;mt<4;mt++)
      #pragma unroll
      for (int pt=0;pt<4;pt++)
        acc[mt][pt] = MFMA(af[mt], bx[pt], acc[mt][pt]);
    __syncthreads();
  }
  #pragma unroll
  for (int mt=0;mt<4;mt++)
    #pragma unroll
    for (int pt=0;pt<4;pt++)
      #pragma unroll
      for (int j=0;j<4;j++) {
        int m = m0 + wm + mt*16 + (lane>>4)*4 + j;
        int pp = p0 + wp + pt*16 + (lane&15);
        if (pp < 1296) out[((size_t)n*256 + m)*1296 + pp] = f2b(acc[mt][pt][j] + bias[m]);
      }
}

// ---------------- fused q/k/v 3x3 convs: stripe-halo implicit GEMM ----------------
// grid (9 stripes, 6 = 3 kinds x 2 m-halves, 8 n), 256 threads (4 waves)
// X staged once per 32-ch chunk with halo; 9 taps read via base + imm offset.
__global__ __launch_bounds__(256,3) void k_conv3(const u16* __restrict__ xin,
        const u16* __restrict__ wq, const u16* __restrict__ wk, const u16* __restrict__ wv,
        u16* __restrict__ qb, u16* __restrict__ kb, u16* __restrict__ vb) {
  // X: [228 pix][40 u16] = 18240 B ; W: 2 x [128 m][40 u16] = 2 x 10240 B
  __shared__ alignas(16) u16 SM[19360];
  char* smem = (char*)SM;
  const int XB = 18240;
  int tid = threadIdx.x, lane = tid & 63, wid = tid >> 6;
  int gr = lane >> 4, li = lane & 15;
  int kind = blockIdx.y >> 1;            // 0=q(SAME), 1=k, 2=v (VALID)
  int m0 = (blockIdx.y & 1) * 128;
  int y0 = blockIdx.x * 4;
  int n = blockIdx.z;
  const u16* wt = (kind==0) ? wq : (kind==1) ? wk : wv;
  const u16* src = xin + (size_t)n*256*1296;
  int mh = wid & 1, ph = wid >> 1;

  // per-lane B-frag base byte offsets (tap offset added as immediate)
  int bb[5];
  #pragma unroll
  for (int i = 0; i < 5; i++) {
    int F = ph*4 + i;
    int p = F*16 + li;
    if (kind == 0) bb[i] = (38*(p/36) + p%36)*80 + gr*16;
    else { int pe = p < 136 ? p : 135; bb[i] = ((pe/34)*38 + pe%34 + 1)*80 + gr*16; }
  }
  int wa[4];
  #pragma unroll
  for (int mf = 0; mf < 4; mf++) wa[mf] = (mh*64 + mf*16 + li)*80 + gr*16;

  f4 z = {0.f,0.f,0.f,0.f};
  f4 acc[4][5];
  #pragma unroll
  for (int a=0;a<4;a++)
    #pragma unroll
    for (int b=0;b<5;b++) acc[a][b] = z;

  int4 r[2];
  #define LOADW(c_, t_) { \
    _Pragma("unroll") \
    for (int s = 0; s < 2; s++) { \
      int slot = tid + s*256, ml = slot >> 2, q4 = slot & 3; \
      r[s] = *(const int4*)&wt[((size_t)((t_)*256 + m0 + ml))*256 + (c_)*32 + q4*8]; \
    } }
  #define WRITEW(pb_) { \
    _Pragma("unroll") \
    for (int s = 0; s < 2; s++) { \
      int slot = tid + s*256, ml = slot >> 2, q4 = slot & 3; \
      *(int4*)(smem + XB + (pb_)*10240 + ml*80 + q4*16) = r[s]; \
    } }
  #define STAGEX(c_) { \
    for (int j = 0; j < 14; j++) { \
      int idx = j*256 + tid; \
      if (idx < 3456) { \
        int cp = idx / 216, pxi = idx - cp*216; \
        int row_l = pxi / 36, xx = pxi - row_l*36; \
        int y = y0 - 1 + row_l; \
        u32 v = 0; \
        if (y >= 0 && y < 36) { \
          u32 a_ = src[(size_t)((c_)*32 + 2*cp)*1296 + y*36 + xx]; \
          u32 b_ = src[(size_t)((c_)*32 + 2*cp + 1)*1296 + y*36 + xx]; \
          v = a_ | (b_ << 16); \
        } \
        *(u32*)(smem + (row_l*38 + xx + 1)*80 + cp*4) = v; \
      } \
    } }

  // zero halo pad columns (cols 0 and 37 of each of 6 rows; only first 64B read)
  if (tid < 192) {
    int pixid = tid >> 4;
    int pix = (pixid >> 1)*38 + (pixid & 1)*37;
    *(u32*)(smem + pix*80 + (tid & 15)*4) = 0;
  }
  STAGEX(0);
  LOADW(0, 0);
  __syncthreads();
  WRITEW(0);
  LOADW(0, 1);
  __syncthreads();
  int pb = 0;

  for (int c = 0; c < 8; c++) {
    #pragma unroll
    for (int t = 0; t < 9; t++) {
      int toff = ((t/3)*38 + (t%3))*80;
      bf8 af[4];
      #pragma unroll
      for (int mf=0;mf<4;mf++) af[mf] = *(bf8*)(smem + XB + pb*10240 + wa[mf]);
      #pragma unroll
      for (int i=0;i<5;i++) {
        bf8 bx = *(bf8*)(smem + bb[i] + toff);
        #pragma unroll
        for (int mf=0;mf<4;mf++) acc[mf][i] = MFMA(af[mf], bx, acc[mf][i]);
      }
      bool last = (c==7) && (t==8);
      if (!last) {
        __syncthreads();
        WRITEW(pb^1);
        if (t == 8) STAGEX(c+1);
        if (!((c==7) && (t>=7))) {
          int t2 = (t+2 < 9) ? t+2 : t-7;
          int c2 = (t+2 < 9) ? c : c+1;
          LOADW(c2, t2);
        }
        __syncthreads();
        pb ^= 1;
      }
    }
  }

  if (kind == 0) {
    #pragma unroll
    for (int mf=0;mf<4;mf++)
      #pragma unroll
      for (int i=0;i<5;i++) {
        int p = (ph*4+i)*16 + li;
        #pragma unroll
        for (int j=0;j<4;j++) {
          int m = m0 + mh*64 + mf*16 + gr*4 + j;
          qb[((size_t)n*256 + m)*1296 + y0*36 + p] = f2b(acc[mf][i][j]);
        }
      }
  } else {
    u16* dst = (kind==1) ? kb : vb;
    #pragma unroll
    for (int mf=0;mf<4;mf++)
      #pragma unroll
      for (int i=0;i<5;i++) {
        int p = (ph*4+i)*16 + li;
        int gp = (y0-1)*34 + p;
        if (p < 136 && gp >= 0 && gp < 1156) {
          #pragma unroll
          for (int j=0;j<4;j++) {
            int m = m0 + mh*64 + mf*16 + gr*4 + j;
            dst[((size_t)n*256 + m)*1156 + gp] = f2b(acc[mf][i][j]);
          }
        }
      }
  }
  #undef LOADW
  #undef WRITEW
  #undef STAGEX
}

// ---------------- flash attention, MFMA, online softmax ----------------
__global__ __launch_bounds__(256,2) void k_attn(const u16* __restrict__ qbf,
        const u16* __restrict__ kbf, const u16* __restrict__ vbf, u16* __restrict__ abf) {
  __shared__ u16 Qs[128][40];
  __shared__ u16 Ks[64][40];
  __shared__ u16 Vs[2][32][40];
  __shared__ u16 Ps[4][2][32][40];
  int tid = threadIdx.x, lane = tid & 63, wid = tid >> 6;
  int h = blockIdx.y, n = blockIdx.z;
  int q0 = blockIdx.x*128;
  const u16* Qp = qbf + ((size_t)n*256 + h*32)*1296;
  const u16* Kp = kbf + ((size_t)n*256 + h*32)*1156;
  const u16* Vp = vbf + ((size_t)n*256 + h*32)*1156;
  #pragma unroll
  for (int j = 0; j < 8; j++) {
    int idx = tid + j*256, qq = idx >> 4, cp = idx & 15;
    int gq = q0 + qq; u32 v = 0;
    if (gq < 1296)
      v = (u32)Qp[(size_t)(2*cp)*1296 + gq] | ((u32)Qp[(size_t)(2*cp+1)*1296 + gq] << 16);
    ((u32*)&Qs[qq][0])[cp] = v;
  }
  f4 z = {0.f,0.f,0.f,0.f};
  float mx[2] = {-1e30f, -1e30f}, ls[2] = {0.f, 0.f};
  f4 accO[2][2] = {{z,z},{z,z}};
  int wq = wid*32;
  __syncthreads();
  for (int d0 = 0; d0 < 1156; d0 += 64) {
    #pragma unroll
    for (int j = 0; j < 4; j++) {
      int idx = tid + j*256, dd = idx >> 4, cp = idx & 15;
      int gd = d0 + dd; u32 v = 0;
      if (gd < 1156)
        v = (u32)Kp[(size_t)(2*cp)*1156 + gd] | ((u32)Kp[(size_t)(2*cp+1)*1156 + gd] << 16);
      ((u32*)&Ks[dd][0])[cp] = v;
    }
    #pragma unroll
    for (int j = 0; j < 4; j++) {
      int idx = tid + j*256, half = idx >> 9, rem = idx & 511;
      int cc = rem >> 4, dp = rem & 15;
      int gd = d0 + half*32 + dp*2; u32 v = 0;
      if (gd < 1156) v = *(const u32*)&Vp[(size_t)cc*1156 + gd];
      ((u32*)&Vs[half][cc][0])[dp] = v;
    }
    __syncthreads();
    bf8 ak[4], bq[2];
    #pragma unroll
    for (int dt=0;dt<4;dt++) ak[dt] = *(bf8*)&Ks[dt*16 + (lane&15)][8*(lane>>4)];
    #pragma unroll
    for (int qt=0;qt<2;qt++) bq[qt] = *(bf8*)&Qs[wq + qt*16 + (lane&15)][8*(lane>>4)];
    f4 s[2][4];
    #pragma unroll
    for (int qt=0;qt<2;qt++)
      #pragma unroll
      for (int dt=0;dt<4;dt++)
        s[qt][dt] = MFMA(ak[dt], bq[qt], z);
    bool tail = (d0 + 64 > 1156);
    #pragma unroll
    for (int qt=0;qt<2;qt++) {
      if (tail) {
        #pragma unroll
        for (int dt=0;dt<4;dt++)
          #pragma unroll
          for (int j=0;j<4;j++)
            if (d0 + dt*16 + (lane>>4)*4 + j >= 1156) s[qt][dt][j] = -1e30f;
      }
      float tm = -1e30f;
      #pragma unroll
      for (int dt=0;dt<4;dt++)
        #pragma unroll
        for (int j=0;j<4;j++) tm = fmaxf(tm, s[qt][dt][j]);
      tm = fmaxf(tm, __shfl_xor(tm, 16));
      tm = fmaxf(tm, __shfl_xor(tm, 32));
      float nm = fmaxf(mx[qt], tm);
      float corr = __expf(mx[qt] - nm);
      mx[qt] = nm;
      float rs = 0.f;
      #pragma unroll
      for (int dt=0;dt<4;dt++)
        #pragma unroll
        for (int j=0;j<4;j++) {
          float e = __expf(s[qt][dt][j] - nm);
          s[qt][dt][j] = e; rs += e;
        }
      rs += __shfl_xor(rs, 16); rs += __shfl_xor(rs, 32);
      ls[qt] = ls[qt]*corr + rs;
      accO[0][qt] *= corr; accO[1][qt] *= corr;
      #pragma unroll
      for (int dt=0;dt<4;dt++) {
        u32 lo_ = cvtpk(s[qt][dt][0], s[qt][dt][1]);
        u32 hi_ = cvtpk(s[qt][dt][2], s[qt][dt][3]);
        u64 pk = (u64)lo_ | ((u64)hi_ << 32);
        *(u64*)&Ps[wid][dt>>1][qt*16 + (lane&15)][(dt&1)*16 + (lane>>4)*4] = pk;
      }
    }
    #pragma unroll
    for (int kt=0;kt<2;kt++) {
      bf8 av0 = *(bf8*)&Vs[kt][(lane&15)][8*(lane>>4)];
      bf8 av1 = *(bf8*)&Vs[kt][16 + (lane&15)][8*(lane>>4)];
      bf8 bp0 = *(bf8*)&Ps[wid][kt][(lane&15)][8*(lane>>4)];
      bf8 bp1 = *(bf8*)&Ps[wid][kt][16 + (lane&15)][8*(lane>>4)];
      accO[0][0] = MFMA(av0, bp0, accO[0][0]);
      accO[0][1] = MFMA(av0, bp1, accO[0][1]);
      accO[1][0] = MFMA(av1, bp0, accO[1][0]);
      accO[1][1] = MFMA(av1, bp1, accO[1][1]);
    }
    __syncthreads();
  }
  #pragma unroll
  for (int qt=0;qt<2;qt++) {
    float inv = 1.f / ls[qt];
    #pragma unroll
    for (int mt=0;mt<2;mt++)
      #pragma unroll
      for (int j=0;j<4;j++) {
        int c = h*32 + mt*16 + (lane>>4)*4 + j;
        int gq = q0 + wq + qt*16 + (lane&15);
        if (gq < 1296) abf[((size_t)n*256 + c)*1296 + gq] = f2b(accO[mt][qt][j] * inv);
      }
  }
}

// ---------------- fused gates GEMM (i,g,o; K=512) + LSTM nonlinearity ----------------
__global__ __launch_bounds__(256,2) void k_gates(const u16* __restrict__ abf,
        const u16* __restrict__ xin, const u16* __restrict__ wg,
        const float* __restrict__ b_g, u16* __restrict__ hn) {
  __shared__ u16 Xs[128][40];
  __shared__ u16 Wg[3][64][40];
  int tid = threadIdx.x, lane = tid & 63, wid = tid >> 6;
  int p0 = blockIdx.x*128, m0 = blockIdx.y*64, n = blockIdx.z;
  int pcol = tid & 127, rg = tid >> 7;
  int p = p0 + pcol;
  f4 z = {0.f,0.f,0.f,0.f};
  f4 acc[3][2][4];
  #pragma unroll
  for (int g=0;g<3;g++)
    #pragma unroll
    for (int mt=0;mt<2;mt++) { acc[g][mt][0]=z; acc[g][mt][1]=z; acc[g][mt][2]=z; acc[g][mt][3]=z; }
  int wm = (wid & 1)*32, wp = (wid >> 1)*64;
  for (int k0 = 0; k0 < 512; k0 += 32) {
    const u16* src = ((k0 < 256) ? abf : xin) + (size_t)n*256*1296 + (size_t)(k0 & 255)*1296;
    #pragma unroll
    for (int it = 0; it < 8; it++) {
      int rp = it*2 + rg, rr = rp*2;
      u32 v = 0;
      if (p < 1296)
        v = (u32)src[(size_t)rr*1296 + p] | ((u32)src[(size_t)(rr+1)*1296 + p] << 16);
      ((u32*)&Xs[pcol][0])[rp] = v;
    }
    #pragma unroll
    for (int j2 = 0; j2 < 12; j2++) {
      int idx = tid + j2*256;
      int g = idx >> 10, rem = idx & 1023, mm = rem >> 4, kc = rem & 15;
      ((u32*)&Wg[g][mm][0])[kc] =
          *(const u32*)&wg[(size_t)g*131072 + (size_t)(m0+mm)*512 + k0 + kc*2];
    }
    __syncthreads();
    bf8 bx[4];
    #pragma unroll
    for (int pt=0;pt<4;pt++) bx[pt] = *(bf8*)&Xs[wp + pt*16 + (lane&15)][8*(lane>>4)];
    #pragma unroll
    for (int g=0;g<3;g++)
      #pragma unroll
      for (int mt=0;mt<2;mt++) {
        bf8 af = *(bf8*)&Wg[g][wm + mt*16 + (lane&15)][8*(lane>>4)];
        #pragma unroll
        for (int pt=0;pt<4;pt++)
          acc[g][mt][pt] = MFMA(af, bx[pt], acc[g][mt][pt]);
      }
    __syncthreads();
  }
  #pragma unroll
  for (int mt=0;mt<2;mt++)
    #pragma unroll
    for (int pt=0;pt<4;pt++)
      #pragma unroll
      for (int j=0;j<4;j++) {
        int r = m0 + wm + mt*16 + (lane>>4)*4 + j;
        int pp = p0 + wp + pt*16 + (lane&15);
        if (pp < 1296) {
          float gi = acc[0][mt][pt][j] + b_g[r];
          float gg = acc[1][mt][pt][j] + b_g[512 + r];
          float go = acc[2][mt][pt][j] + b_g[768 + r];
          float hv = sigm(go) * tanhf(sigm(gi) * tanhf(gg));
          hn[((size_t)n*256 + r)*1296 + pp] = f2b(hv);
        }
      }
}

// ---------------- out GEMM: M=256,K=256 over hn bf16, out fp32 ----------------
__global__ __launch_bounds__(256,2) void k_out(const u16* __restrict__ hn,
        const u16* __restrict__ wb, const float* __restrict__ bias,
        float* __restrict__ out) {
  __shared__ u16 Xs[128][40];
  __shared__ u16 Ws[128][40];
  int tid = threadIdx.x, lane = tid & 63, wid = tid >> 6;
  int p0 = blockIdx.x*128, m0 = blockIdx.y*128, n = blockIdx.z;
  int pcol = tid & 127, rg = tid >> 7;
  int p = p0 + pcol;
  const u16* src = hn + (size_t)n*256*1296;
  f4 z = {0.f,0.f,0.f,0.f};
  f4 acc[4][4];
  #pragma unroll
  for (int i=0;i<4;i++) { acc[i][0]=z; acc[i][1]=z; acc[i][2]=z; acc[i][3]=z; }
  int wm = (wid & 1)*64, wp = (wid >> 1)*64;
  for (int k0 = 0; k0 < 256; k0 += 32) {
    #pragma unroll
    for (int it = 0; it < 8; it++) {
      int rp = it*2 + rg, rr = k0 + rp*2;
      u32 v = 0;
      if (p < 1296)
        v = (u32)src[(size_t)rr*1296 + p] | ((u32)src[(size_t)(rr+1)*1296 + p] << 16);
      ((u32*)&Xs[pcol][0])[rp] = v;
    }
    #pragma unroll
    for (int j2 = 0; j2 < 8; j2++) {
      int idx = tid + j2*256, mm = idx >> 4, rc = idx & 15;
      ((u32*)&Ws[mm][0])[rc] = *(const u32*)&wb[(size_t)(m0+mm)*256 + k0 + rc*2];
    }
    __syncthreads();
    bf8 af[4], bx[4];
    #pragma unroll
    for (int mt=0;mt<4;mt++) af[mt] = *(bf8*)&Ws[wm + mt*16 + (lane&15)][8*(lane>>4)];
    #pragma unroll
    for (int pt=0;pt<4;pt++) bx[pt] = *(bf8*)&Xs[wp + pt*16 + (lane&15)][8*(lane>>4)];
    #pragma unroll
    for (int mt=0;mt<4;mt++)
      #pragma unroll
      for (int pt=0;pt<4;pt++)
        acc[mt][pt] = MFMA(af[mt], bx[pt], acc[mt][pt]);
    __syncthreads();
  }
  #pragma unroll
  for (int mt=0;mt<4;mt++)
    #pragma unroll
    for (int pt=0;pt<4;pt++)
      #pragma unroll
      for (int j=0;j<4;j++) {
        int m = m0 + wm + mt*16 + (lane>>4)*4 + j;
        int pp = p0 + wp + pt*16 + (lane&15);
        if (pp < 1296) out[((size_t)n*256 + m)*1296 + pp] = acc[mt][pt][j] + bias[m];
      }
}

extern "C" void kernel_launch(void* const* d_in, const int* in_sizes, int n_in,
                              void* d_out, int out_size, void* d_ws, size_t ws_size,
                              hipStream_t stream) {
  const float* x     = (const float*)d_in[0];
  const float* w_in  = (const float*)d_in[1];
  const float* b_in  = (const float*)d_in[2];
  const float* w_qx  = (const float*)d_in[3];
  const float* w_kx  = (const float*)d_in[5];
  const float* w_vx  = (const float*)d_in[7];
  const float* w_ga  = (const float*)d_in[9];
  const float* b_g   = (const float*)d_in[10];
  const float* w_gx  = (const float*)d_in[11];
  const float* w_out = (const float*)d_in[13];
  const float* b_out = (const float*)d_in[14];
  float* out = (float*)d_out;

  u16* ws = (u16*)d_ws;
  size_t o = 0;
  u16* xin_bf = ws + o; o += 2654208;   // [8][256][1296]
  u16* qbuf   = ws + o; o += 2654208;
  u16* kbuf   = ws + o; o += 2367488;   // [8][256][1156]
  u16* vbuf   = ws + o; o += 2367488;
  u16* abuf   = ws + o; o += 2654208;
  u16* hnb    = ws + o; o += 2654208;
  u16* wqT    = ws + o; o += 589824;    // [9][256][256]
  u16* wkT    = ws + o; o += 589824;
  u16* wvT    = ws + o; o += 589824;
  u16* wgT    = ws + o; o += 393216;    // [3][256][512]
  u16* winb   = ws + o; o += 32768;
  u16* woutb  = ws + o; o += 65536;

  k_cvt<<<128, 256, 0, stream>>>(w_in, winb, 32768);
  k_cvt<<<256, 256, 0, stream>>>(w_out, woutb, 65536);
  k_wt3<<<dim3(2304,3), 256, 0, stream>>>(w_qx, w_kx, w_vx, wqT, wkT, wvT);
  k_wtg<<<1536, 256, 0, stream>>>(w_ga, w_gx, wgT);

  k_xin  <<<dim3(11,2,8), 256, 0, stream>>>(x, winb, b_in, xin_bf);
  k_conv3<<<dim3(9,6,8), 256, 0, stream>>>(xin_bf, wqT, wkT, wvT, qbuf, kbuf, vbuf);
  k_attn <<<dim3(11,8,8), 256, 0, stream>>>(qbuf, kbuf, vbuf, abuf);
  k_gates<<<dim3(11,4,8), 256, 0, stream>>>(abuf, xin_bf, wgT, b_g, hnb);
  k_out  <<<dim3(11,2,8), 256, 0, stream>>>(hnb, woutb, b_out, out);
}

// Round 5
// 259.924 us; speedup vs baseline: 1.7648x; 1.7648x over previous
//
#include <hip/hip_runtime.h>
#include <math.h>

typedef unsigned int u32;
typedef unsigned short u16;
typedef unsigned long long u64;
typedef __attribute__((ext_vector_type(8))) __bf16 bf8;
typedef __attribute__((ext_vector_type(4))) float f4;

#define MFMA(a,b,c) __builtin_amdgcn_mfma_f32_16x16x32_bf16(a,b,c,0,0,0)

static __device__ __forceinline__ u32 cvtpk(float lo, float hi) {
  u32 r; asm("v_cvt_pk_bf16_f32 %0, %1, %2" : "=v"(r) : "v"(lo), "v"(hi));
  return r;
}
static __device__ __forceinline__ u16 f2b(float x) { return (u16)cvtpk(x, 0.f); }
static __device__ __forceinline__ float sigm(float x) { return 1.f/(1.f+__expf(-x)); }

// All [256ch][P] bf16 intermediates are PAIR-INTERLEAVED: [128 pair][P][2],
// i.e. element (ch,p) at ((ch>>1)*P + p)*2 + (ch&1); u32 view: pair q at q*P+p.
// Exception: vbuf stays plain [256][1156] (attention reads V along d).

// ---------------- weight transforms (bf16, once per call) ----------------
__global__ __launch_bounds__(256) void k_cvt(const float* __restrict__ in,
        u16* __restrict__ out, int n) {
  int i = blockIdx.x*256 + threadIdx.x;
  if (i < n) out[i] = f2b(in[i]);
}
// conv weight [256][256*9] -> tap-major [9][256][256]
__global__ __launch_bounds__(256) void k_wt3(const float* __restrict__ wq,
        const float* __restrict__ wk, const float* __restrict__ wv,
        u16* __restrict__ tq, u16* __restrict__ tk, u16* __restrict__ tv) {
  const float* w = (blockIdx.y==0)?wq:(blockIdx.y==1)?wk:wv;
  u16* wt = (blockIdx.y==0)?tq:(blockIdx.y==1)?tk:tv;
  int i = blockIdx.x*256 + threadIdx.x;
  int tap = i >> 16, mm = (i & 65535) >> 8, rr = i & 255;
  wt[i] = f2b(w[(size_t)mm*2304 + rr*9 + tap]);
}
// gates: [3 gates i,g,o][256 rows][512 k]
__global__ __launch_bounds__(256) void k_wtg(const float* __restrict__ w_ga,
        const float* __restrict__ w_gx, u16* __restrict__ wg) {
  int i = blockIdx.x*256 + threadIdx.x;
  int g = i >> 17, rem = i & 131071, rr = rem >> 9, kk = rem & 511;
  int gb = (g == 0) ? 0 : (g == 1) ? 512 : 768;
  float v = (kk < 256) ? w_ga[(size_t)(gb+rr)*256 + kk]
                       : w_gx[(size_t)(gb+rr)*256 + kk - 256];
  wg[i] = f2b(v);
}

// ---------------- xin GEMM: M=256,K=128 over x fp32 -> pair-interleaved bf16 ----
__global__ __launch_bounds__(256,2) void k_xin(const float* __restrict__ x,
        const u16* __restrict__ wb, const float* __restrict__ bias,
        u16* __restrict__ out) {
  __shared__ u16 Xs[128][40];
  __shared__ u16 Ws[128][40];
  int tid = threadIdx.x, lane = tid & 63, wid = tid >> 6;
  int li = lane & 15, gr = lane >> 4;
  int p0 = blockIdx.x*128, m0 = blockIdx.y*128, n = blockIdx.z;
  int pcol = tid & 127, rg = tid >> 7;
  int p = p0 + pcol;
  const float* src = x + (size_t)n*128*1296;
  f4 z = {0.f,0.f,0.f,0.f};
  f4 acc[4][4];
  #pragma unroll
  for (int i=0;i<4;i++) { acc[i][0]=z; acc[i][1]=z; acc[i][2]=z; acc[i][3]=z; }
  int wm = (wid & 1)*64, wp = (wid >> 1)*64;
  for (int k0 = 0; k0 < 128; k0 += 32) {
    #pragma unroll
    for (int it = 0; it < 8; it++) {
      int rp = it*2 + rg, rr = k0 + rp*2;
      float a = 0.f, b = 0.f;
      if (p < 1296) { a = src[(size_t)rr*1296+p]; b = src[(size_t)(rr+1)*1296+p]; }
      ((u32*)&Xs[pcol][0])[rp] = cvtpk(a, b);
    }
    #pragma unroll
    for (int j2 = 0; j2 < 8; j2++) {
      int idx = tid + j2*256, mm = idx >> 4, rc = idx & 15;
      ((u32*)&Ws[mm][0])[rc] = *(const u32*)&wb[(size_t)(m0+mm)*128 + k0 + rc*2];
    }
    __syncthreads();
    bf8 af[4], bx[4];
    #pragma unroll
    for (int mt=0;mt<4;mt++) af[mt] = *(bf8*)&Ws[wm + mt*16 + li][8*gr];
    #pragma unroll
    for (int pt=0;pt<4;pt++) bx[pt] = *(bf8*)&Xs[wp + pt*16 + li][8*gr];
    #pragma unroll
    for (int mt=0;mt<4;mt++)
      #pragma unroll
      for (int pt=0;pt<4;pt++)
        acc[mt][pt] = MFMA(af[mt], bx[pt], acc[mt][pt]);
    __syncthreads();
  }
  u32* out32 = (u32*)out + (size_t)n*128*1296;
  #pragma unroll
  for (int mt=0;mt<4;mt++)
    #pragma unroll
    for (int pt=0;pt<4;pt++) {
      int mb = m0 + wm + mt*16 + gr*4;
      int pp = p0 + wp + pt*16 + li;
      if (pp < 1296) {
        out32[(size_t)(mb>>1)*1296 + pp] = cvtpk(acc[mt][pt][0]+bias[mb], acc[mt][pt][1]+bias[mb+1]);
        out32[(size_t)((mb>>1)+1)*1296 + pp] = cvtpk(acc[mt][pt][2]+bias[mb+2], acc[mt][pt][3]+bias[mb+3]);
      }
    }
}

// ------- fused q/k/v 3x3 convs: tap-major implicit GEMM, dbuf + reg prefetch -------
__global__ __launch_bounds__(256,3) void k_conv3(const u16* __restrict__ xin,
        const u16* __restrict__ wq, const u16* __restrict__ wk, const u16* __restrict__ wv,
        u16* __restrict__ qb, u16* __restrict__ kb, u16* __restrict__ vb) {
  __shared__ u16 Xs[2][128][40];
  __shared__ u16 Ws[2][128][40];
  int tid = threadIdx.x, lane = tid & 63, wid = tid >> 6;
  int li = lane & 15, gr = lane >> 4;
  int kind = blockIdx.y >> 1;            // 0=q(SAME), 1=k, 2=v (VALID)
  int m0 = (blockIdx.y & 1)*128;
  int n = blockIdx.z;
  int P  = (kind == 0) ? 1296 : 1156;
  int WO = (kind == 0) ? 36 : 34;
  int pad = (kind == 0) ? 1 : 0;
  int p0 = blockIdx.x*128;
  if (p0 >= P) return;
  const u16* wt = (kind==0) ? wq : (kind==1) ? wk : wv;
  const u32* src32 = (const u32*)xin + (size_t)n*128*1296;
  const u32* wt32 = (const u32*)wt;      // [9*256][128] u32 view
  int pcol = tid & 127, rg = tid >> 7;
  int p = p0 + pcol;
  int py = 0, px = 0;
  if (p < P) { py = p / WO; px = p % WO; }
  f4 z = {0.f,0.f,0.f,0.f};
  f4 acc[4][4];
  #pragma unroll
  for (int i=0;i<4;i++) { acc[i][0]=z; acc[i][1]=z; acc[i][2]=z; acc[i][3]=z; }
  int wm = (wid & 1)*64, wp = (wid >> 1)*64;
  u32 rx[8], rw[8];

  #define LOADIT(tap_, r0_) { \
    int dy = (tap_)/3 - pad, dx = (tap_)%3 - pad; \
    int sy = py + dy, sx = px + dx; \
    bool ok = (p < P) && sy >= 0 && sy < 36 && sx >= 0 && sx < 36; \
    int soff = sy*36 + sx; \
    const u32* xs = src32 + (size_t)((r0_)>>1)*1296 + soff; \
    _Pragma("unroll") \
    for (int it2 = 0; it2 < 8; it2++) { \
      int rp = it2*2 + rg; \
      rx[it2] = ok ? xs[(size_t)rp*1296] : 0u; \
    } \
    const u32* wsrc = wt32 + ((size_t)((tap_)*256 + m0))*128 + ((r0_)>>1); \
    _Pragma("unroll") \
    for (int j2 = 0; j2 < 8; j2++) { \
      int idx = tid + j2*256, mm = idx >> 4, rc = idx & 15; \
      rw[j2] = wsrc[(size_t)mm*128 + rc]; \
    } }

  LOADIT(0, 0);
  int pb = 0;
  for (int it = 0; it < 72; it++) {
    // write current regs -> LDS[pb] (vmcnt wait lands here, after prev MFMA)
    #pragma unroll
    for (int it2 = 0; it2 < 8; it2++) {
      int rp = it2*2 + rg;
      *(u32*)&Xs[pb][pcol][rp*2] = rx[it2];
    }
    #pragma unroll
    for (int j2 = 0; j2 < 8; j2++) {
      int idx = tid + j2*256, mm = idx >> 4, rc = idx & 15;
      *(u32*)&Ws[pb][mm][rc*2] = rw[j2];
    }
    __syncthreads();
    if (it < 71) {
      int nt = it + 1;
      LOADIT(nt >> 3, (nt & 7)*32);      // issue next-iter loads; overlap with MFMA
    }
    bf8 af[4], bx[4];
    #pragma unroll
    for (int mt=0;mt<4;mt++) af[mt] = *(bf8*)&Ws[pb][wm + mt*16 + li][8*gr];
    #pragma unroll
    for (int pt=0;pt<4;pt++) bx[pt] = *(bf8*)&Xs[pb][wp + pt*16 + li][8*gr];
    #pragma unroll
    for (int mt=0;mt<4;mt++)
      #pragma unroll
      for (int pt=0;pt<4;pt++)
        acc[mt][pt] = MFMA(af[mt], bx[pt], acc[mt][pt]);
    pb ^= 1;
  }
  #undef LOADIT

  if (kind <= 1) {
    u32* dst32 = (u32*)(kind==0 ? qb : kb) + (size_t)n*128*P;
    #pragma unroll
    for (int mt=0;mt<4;mt++)
      #pragma unroll
      for (int pt=0;pt<4;pt++) {
        int mb = m0 + wm + mt*16 + gr*4;
        int pp = p0 + wp + pt*16 + li;
        if (pp < P) {
          dst32[(size_t)(mb>>1)*P + pp] = cvtpk(acc[mt][pt][0], acc[mt][pt][1]);
          dst32[(size_t)((mb>>1)+1)*P + pp] = cvtpk(acc[mt][pt][2], acc[mt][pt][3]);
        }
      }
  } else {
    #pragma unroll
    for (int mt=0;mt<4;mt++)
      #pragma unroll
      for (int pt=0;pt<4;pt++) {
        int pp = p0 + wp + pt*16 + li;
        if (pp < P) {
          #pragma unroll
          for (int j=0;j<4;j++) {
            int m = m0 + wm + mt*16 + gr*4 + j;
            vb[((size_t)n*256 + m)*1156 + pp] = f2b(acc[mt][pt][j]);
          }
        }
      }
  }
}

// ---------------- flash attention, MFMA, online softmax ----------------
__global__ __launch_bounds__(256,2) void k_attn(const u16* __restrict__ qbf,
        const u16* __restrict__ kbf, const u16* __restrict__ vbf, u16* __restrict__ abf) {
  __shared__ u16 Qs[128][40];
  __shared__ u16 Ks[64][40];
  __shared__ u16 Vs[2][32][40];
  __shared__ u16 Ps[4][2][32][40];
  int tid = threadIdx.x, lane = tid & 63, wid = tid >> 6;
  int li = lane & 15, gr = lane >> 4;
  int h = blockIdx.y, n = blockIdx.z;
  int q0 = blockIdx.x*128;
  const u32* Qp32 = (const u32*)qbf + ((size_t)n*128 + h*16)*1296;
  const u32* Kp32 = (const u32*)kbf + ((size_t)n*128 + h*16)*1156;
  const u16* Vp = vbf + ((size_t)n*256 + h*32)*1156;
  #pragma unroll
  for (int j = 0; j < 8; j++) {
    int idx = tid + j*256, qq = idx >> 4, cp = idx & 15;
    int gq = q0 + qq;
    ((u32*)&Qs[qq][0])[cp] = (gq < 1296) ? Qp32[(size_t)cp*1296 + gq] : 0u;
  }
  f4 z = {0.f,0.f,0.f,0.f};
  float mx[2] = {-1e30f, -1e30f}, ls[2] = {0.f, 0.f};
  f4 accO[2][2] = {{z,z},{z,z}};
  int wq = wid*32;
  __syncthreads();
  for (int d0 = 0; d0 < 1156; d0 += 64) {
    #pragma unroll
    for (int j = 0; j < 4; j++) {
      int idx = tid + j*256, dd = idx >> 4, cp = idx & 15;
      int gd = d0 + dd;
      ((u32*)&Ks[dd][0])[cp] = (gd < 1156) ? Kp32[(size_t)cp*1156 + gd] : 0u;
    }
    #pragma unroll
    for (int j = 0; j < 4; j++) {
      int idx = tid + j*256, half = idx >> 9, rem = idx & 511;
      int cc = rem >> 4, dp = rem & 15;
      int gd = d0 + half*32 + dp*2; u32 v = 0;
      if (gd < 1156) v = *(const u32*)&Vp[(size_t)cc*1156 + gd];
      ((u32*)&Vs[half][cc][0])[dp] = v;
    }
    __syncthreads();
    bf8 ak[4], bq[2];
    #pragma unroll
    for (int dt=0;dt<4;dt++) ak[dt] = *(bf8*)&Ks[dt*16 + li][8*gr];
    #pragma unroll
    for (int qt=0;qt<2;qt++) bq[qt] = *(bf8*)&Qs[wq + qt*16 + li][8*gr];
    f4 s[2][4];
    #pragma unroll
    for (int qt=0;qt<2;qt++)
      #pragma unroll
      for (int dt=0;dt<4;dt++)
        s[qt][dt] = MFMA(ak[dt], bq[qt], z);
    bool tail = (d0 + 64 > 1156);
    #pragma unroll
    for (int qt=0;qt<2;qt++) {
      if (tail) {
        #pragma unroll
        for (int dt=0;dt<4;dt++)
          #pragma unroll
          for (int j=0;j<4;j++)
            if (d0 + dt*16 + gr*4 + j >= 1156) s[qt][dt][j] = -1e30f;
      }
      float tm = -1e30f;
      #pragma unroll
      for (int dt=0;dt<4;dt++)
        #pragma unroll
        for (int j=0;j<4;j++) tm = fmaxf(tm, s[qt][dt][j]);
      tm = fmaxf(tm, __shfl_xor(tm, 16));
      tm = fmaxf(tm, __shfl_xor(tm, 32));
      float nm = fmaxf(mx[qt], tm);
      float corr = __expf(mx[qt] - nm);
      mx[qt] = nm;
      float rs = 0.f;
      #pragma unroll
      for (int dt=0;dt<4;dt++)
        #pragma unroll
        for (int j=0;j<4;j++) {
          float e = __expf(s[qt][dt][j] - nm);
          s[qt][dt][j] = e; rs += e;
        }
      rs += __shfl_xor(rs, 16); rs += __shfl_xor(rs, 32);
      ls[qt] = ls[qt]*corr + rs;
      accO[0][qt] *= corr; accO[1][qt] *= corr;
      #pragma unroll
      for (int dt=0;dt<4;dt++) {
        u32 lo_ = cvtpk(s[qt][dt][0], s[qt][dt][1]);
        u32 hi_ = cvtpk(s[qt][dt][2], s[qt][dt][3]);
        u64 pk = (u64)lo_ | ((u64)hi_ << 32);
        *(u64*)&Ps[wid][dt>>1][qt*16 + li][(dt&1)*16 + gr*4] = pk;
      }
    }
    #pragma unroll
    for (int kt=0;kt<2;kt++) {
      bf8 av0 = *(bf8*)&Vs[kt][li][8*gr];
      bf8 av1 = *(bf8*)&Vs[kt][16 + li][8*gr];
      bf8 bp0 = *(bf8*)&Ps[wid][kt][li][8*gr];
      bf8 bp1 = *(bf8*)&Ps[wid][kt][16 + li][8*gr];
      accO[0][0] = MFMA(av0, bp0, accO[0][0]);
      accO[0][1] = MFMA(av0, bp1, accO[0][1]);
      accO[1][0] = MFMA(av1, bp0, accO[1][0]);
      accO[1][1] = MFMA(av1, bp1, accO[1][1]);
    }
    __syncthreads();
  }
  u32* ab32 = (u32*)abf + (size_t)n*128*1296;
  #pragma unroll
  for (int qt=0;qt<2;qt++) {
    float inv = 1.f / ls[qt];
    #pragma unroll
    for (int mt=0;mt<2;mt++) {
      int cb = h*32 + mt*16 + gr*4;
      int gq = q0 + wq + qt*16 + li;
      if (gq < 1296) {
        ab32[(size_t)(cb>>1)*1296 + gq] = cvtpk(accO[mt][qt][0]*inv, accO[mt][qt][1]*inv);
        ab32[(size_t)((cb>>1)+1)*1296 + gq] = cvtpk(accO[mt][qt][2]*inv, accO[mt][qt][3]*inv);
      }
    }
  }
}

// ---------------- fused gates GEMM (i,g,o; K=512) + LSTM nonlinearity ----------------
__global__ __launch_bounds__(256,2) void k_gates(const u16* __restrict__ abf,
        const u16* __restrict__ xin, const u16* __restrict__ wg,
        const float* __restrict__ b_g, u16* __restrict__ hn) {
  __shared__ u16 Xs[128][40];
  __shared__ u16 Wg[3][64][40];
  int tid = threadIdx.x, lane = tid & 63, wid = tid >> 6;
  int li = lane & 15, gr = lane >> 4;
  int p0 = blockIdx.x*128, m0 = blockIdx.y*64, n = blockIdx.z;
  int pcol = tid & 127, rg = tid >> 7;
  int p = p0 + pcol;
  f4 z = {0.f,0.f,0.f,0.f};
  f4 acc[3][2][4];
  #pragma unroll
  for (int g=0;g<3;g++)
    #pragma unroll
    for (int mt=0;mt<2;mt++) { acc[g][mt][0]=z; acc[g][mt][1]=z; acc[g][mt][2]=z; acc[g][mt][3]=z; }
  int wm = (wid & 1)*32, wp = (wid >> 1)*64;
  for (int k0 = 0; k0 < 512; k0 += 32) {
    const u32* src32 = (const u32*)((k0 < 256) ? abf : xin)
        + (size_t)n*128*1296 + (size_t)((k0 & 255)>>1)*1296;
    #pragma unroll
    for (int it = 0; it < 8; it++) {
      int rp = it*2 + rg;
      ((u32*)&Xs[pcol][0])[rp] = (p < 1296) ? src32[(size_t)rp*1296 + p] : 0u;
    }
    #pragma unroll
    for (int j2 = 0; j2 < 12; j2++) {
      int idx = tid + j2*256;
      int g = idx >> 10, rem = idx & 1023, mm = rem >> 4, kc = rem & 15;
      ((u32*)&Wg[g][mm][0])[kc] =
          *(const u32*)&wg[(size_t)g*131072 + (size_t)(m0+mm)*512 + k0 + kc*2];
    }
    __syncthreads();
    bf8 bx[4];
    #pragma unroll
    for (int pt=0;pt<4;pt++) bx[pt] = *(bf8*)&Xs[wp + pt*16 + li][8*gr];
    #pragma unroll
    for (int g=0;g<3;g++)
      #pragma unroll
      for (int mt=0;mt<2;mt++) {
        bf8 af = *(bf8*)&Wg[g][wm + mt*16 + li][8*gr];
        #pragma unroll
        for (int pt=0;pt<4;pt++)
          acc[g][mt][pt] = MFMA(af, bx[pt], acc[g][mt][pt]);
      }
    __syncthreads();
  }
  u32* hn32 = (u32*)hn + (size_t)n*128*1296;
  #pragma unroll
  for (int mt=0;mt<2;mt++)
    #pragma unroll
    for (int pt=0;pt<4;pt++) {
      int rb = m0 + wm + mt*16 + gr*4;
      int pp = p0 + wp + pt*16 + li;
      if (pp < 1296) {
        float hv[4];
        #pragma unroll
        for (int j=0;j<4;j++) {
          float gi = acc[0][mt][pt][j] + b_g[rb+j];
          float gg = acc[1][mt][pt][j] + b_g[512 + rb+j];
          float go = acc[2][mt][pt][j] + b_g[768 + rb+j];
          hv[j] = sigm(go) * tanhf(sigm(gi) * tanhf(gg));
        }
        hn32[(size_t)(rb>>1)*1296 + pp] = cvtpk(hv[0], hv[1]);
        hn32[(size_t)((rb>>1)+1)*1296 + pp] = cvtpk(hv[2], hv[3]);
      }
    }
}

// ---------------- out GEMM: M=256,K=256 over hn (pair-interleaved), out fp32 -------
__global__ __launch_bounds__(256,2) void k_out(const u16* __restrict__ hn,
        const u16* __restrict__ wb, const float* __restrict__ bias,
        float* __restrict__ out) {
  __shared__ u16 Xs[128][40];
  __shared__ u16 Ws[128][40];
  int tid = threadIdx.x, lane = tid & 63, wid = tid >> 6;
  int li = lane & 15, gr = lane >> 4;
  int p0 = blockIdx.x*128, m0 = blockIdx.y*128, n = blockIdx.z;
  int pcol = tid & 127, rg = tid >> 7;
  int p = p0 + pcol;
  const u32* src32 = (const u32*)hn + (size_t)n*128*1296;
  f4 z = {0.f,0.f,0.f,0.f};
  f4 acc[4][4];
  #pragma unroll
  for (int i=0;i<4;i++) { acc[i][0]=z; acc[i][1]=z; acc[i][2]=z; acc[i][3]=z; }
  int wm = (wid & 1)*64, wp = (wid >> 1)*64;
  for (int k0 = 0; k0 < 256; k0 += 32) {
    #pragma unroll
    for (int it = 0; it < 8; it++) {
      int rp = it*2 + rg;
      ((u32*)&Xs[pcol][0])[rp] =
          (p < 1296) ? src32[(size_t)((k0>>1) + rp)*1296 + p] : 0u;
    }
    #pragma unroll
    for (int j2 = 0; j2 < 8; j2++) {
      int idx = tid + j2*256, mm = idx >> 4, rc = idx & 15;
      ((u32*)&Ws[mm][0])[rc] = *(const u32*)&wb[(size_t)(m0+mm)*256 + k0 + rc*2];
    }
    __syncthreads();
    bf8 af[4], bx[4];
    #pragma unroll
    for (int mt=0;mt<4;mt++) af[mt] = *(bf8*)&Ws[wm + mt*16 + li][8*gr];
    #pragma unroll
    for (int pt=0;pt<4;pt++) bx[pt] = *(bf8*)&Xs[wp + pt*16 + li][8*gr];
    #pragma unroll
    for (int mt=0;mt<4;mt++)
      #pragma unroll
      for (int pt=0;pt<4;pt++)
        acc[mt][pt] = MFMA(af[mt], bx[pt], acc[mt][pt]);
    __syncthreads();
  }
  #pragma unroll
  for (int mt=0;mt<4;mt++)
    #pragma unroll
    for (int pt=0;pt<4;pt++)
      #pragma unroll
      for (int j=0;j<4;j++) {
        int m = m0 + wm + mt*16 + gr*4 + j;
        int pp = p0 + wp + pt*16 + li;
        if (pp < 1296) out[((size_t)n*256 + m)*1296 + pp] = acc[mt][pt][j] + bias[m];
      }
}

extern "C" void kernel_launch(void* const* d_in, const int* in_sizes, int n_in,
                              void* d_out, int out_size, void* d_ws, size_t ws_size,
                              hipStream_t stream) {
  const float* x     = (const float*)d_in[0];
  const float* w_in  = (const float*)d_in[1];
  const float* b_in  = (const float*)d_in[2];
  const float* w_qx  = (const float*)d_in[3];
  const float* w_kx  = (const float*)d_in[5];
  const float* w_vx  = (const float*)d_in[7];
  const float* w_ga  = (const float*)d_in[9];
  const float* b_g   = (const float*)d_in[10];
  const float* w_gx  = (const float*)d_in[11];
  const float* w_out = (const float*)d_in[13];
  const float* b_out = (const float*)d_in[14];
  float* out = (float*)d_out;

  u16* ws = (u16*)d_ws;
  size_t o = 0;
  u16* xin_bf = ws + o; o += 2654208;   // [8][128 pair][1296][2]
  u16* qbuf   = ws + o; o += 2654208;   // pair-interleaved
  u16* kbuf   = ws + o; o += 2367488;   // pair-interleaved
  u16* vbuf   = ws + o; o += 2367488;   // plain [256][1156]
  u16* abuf   = ws + o; o += 2654208;   // pair-interleaved
  u16* hnb    = ws + o; o += 2654208;   // pair-interleaved
  u16* wqT    = ws + o; o += 589824;    // [9][256][256]
  u16* wkT    = ws + o; o += 589824;
  u16* wvT    = ws + o; o += 589824;
  u16* wgT    = ws + o; o += 393216;    // [3][256][512]
  u16* winb   = ws + o; o += 32768;
  u16* woutb  = ws + o; o += 65536;

  k_cvt<<<128, 256, 0, stream>>>(w_in, winb, 32768);
  k_cvt<<<256, 256, 0, stream>>>(w_out, woutb, 65536);
  k_wt3<<<dim3(2304,3), 256, 0, stream>>>(w_qx, w_kx, w_vx, wqT, wkT, wvT);
  k_wtg<<<1536, 256, 0, stream>>>(w_ga, w_gx, wgT);

  k_xin  <<<dim3(11,2,8), 256, 0, stream>>>(x, winb, b_in, xin_bf);
  k_conv3<<<dim3(11,6,8), 256, 0, stream>>>(xin_bf, wqT, wkT, wvT, qbuf, kbuf, vbuf);
  k_attn <<<dim3(11,8,8), 256, 0, stream>>>(qbuf, kbuf, vbuf, abuf);
  k_gates<<<dim3(11,4,8), 256, 0, stream>>>(abuf, xin_bf, wgT, b_g, hnb);
  k_out  <<<dim3(11,2,8), 256, 0, stream>>>(hnb, woutb, b_out, out);
}

// Round 6
// 222.786 us; speedup vs baseline: 2.0590x; 1.1667x over previous
//
#include <hip/hip_runtime.h>
#include <math.h>

typedef unsigned int u32;
typedef unsigned short u16;
typedef unsigned long long u64;
typedef __attribute__((ext_vector_type(8))) __bf16 bf8;
typedef __attribute__((ext_vector_type(4))) float f4;

#define MFMA(a,b,c) __builtin_amdgcn_mfma_f32_16x16x32_bf16(a,b,c,0,0,0)

// chunk swizzle: 16B chunk c of row stored at SWC(row,c); involution, applied
// on write AND read. Breaks the {row,row+8,row+16,...} stride-80B bank alias.
#define SWC(row_, c_) ((((((c_)>>1) ^ (((row_)>>3)&1))<<1) | (((c_)&1) ^ (((row_)>>4)&1))))

static __device__ __forceinline__ u32 cvtpk(float lo, float hi) {
  u32 r; asm("v_cvt_pk_bf16_f32 %0, %1, %2" : "=v"(r) : "v"(lo), "v"(hi));
  return r;
}
static __device__ __forceinline__ u16 f2b(float x) { return (u16)cvtpk(x, 0.f); }
static __device__ __forceinline__ float sigm(float x) { return 1.f/(1.f+__expf(-x)); }

// All [256ch][P] bf16 intermediates are PAIR-INTERLEAVED: u32 pair q at q*P+p.
// Exception: vbuf plain [256][1156].

// ---------------- weight transforms ----------------
__global__ __launch_bounds__(256) void k_cvt(const float* __restrict__ in,
        u16* __restrict__ out, int n) {
  int i = blockIdx.x*256 + threadIdx.x;
  if (i < n) out[i] = f2b(in[i]);
}
__global__ __launch_bounds__(256) void k_wt3(const float* __restrict__ wq,
        const float* __restrict__ wk, const float* __restrict__ wv,
        u16* __restrict__ tq, u16* __restrict__ tk, u16* __restrict__ tv) {
  const float* w = (blockIdx.y==0)?wq:(blockIdx.y==1)?wk:wv;
  u16* wt = (blockIdx.y==0)?tq:(blockIdx.y==1)?tk:tv;
  int i = blockIdx.x*256 + threadIdx.x;
  int tap = i >> 16, mm = (i & 65535) >> 8, rr = i & 255;
  wt[i] = f2b(w[(size_t)mm*2304 + rr*9 + tap]);
}
__global__ __launch_bounds__(256) void k_wtg(const float* __restrict__ w_ga,
        const float* __restrict__ w_gx, u16* __restrict__ wg) {
  int i = blockIdx.x*256 + threadIdx.x;
  int g = i >> 17, rem = i & 131071, rr = rem >> 9, kk = rem & 511;
  int gb = (g == 0) ? 0 : (g == 1) ? 512 : 768;
  float v = (kk < 256) ? w_ga[(size_t)(gb+rr)*256 + kk]
                       : w_gx[(size_t)(gb+rr)*256 + kk - 256];
  wg[i] = f2b(v);
}

// ---------------- xin GEMM: M=256,K=128 over x fp32 -> pair-interleaved bf16 ----
__global__ __launch_bounds__(256,2) void k_xin(const float* __restrict__ x,
        const u16* __restrict__ wb, const float* __restrict__ bias,
        u16* __restrict__ out) {
  __shared__ u16 Xs[128][40];
  __shared__ u16 Ws[128][40];
  int tid = threadIdx.x, lane = tid & 63, wid = tid >> 6;
  int li = lane & 15, gr = lane >> 4;
  int p0 = blockIdx.x*128, m0 = blockIdx.y*128, n = blockIdx.z;
  int pcol = tid & 127, rg = tid >> 7;
  int wrow = tid >> 1, wh = tid & 1;
  int p = p0 + pcol;
  const float* src = x + (size_t)n*128*1296;
  const u32* wb32 = (const u32*)wb;
  f4 z = {0.f,0.f,0.f,0.f};
  f4 acc[4][4];
  #pragma unroll
  for (int i=0;i<4;i++) { acc[i][0]=z; acc[i][1]=z; acc[i][2]=z; acc[i][3]=z; }
  int wm = (wid & 1)*64, wp = (wid >> 1)*64;
  for (int k0 = 0; k0 < 128; k0 += 32) {
    u32 rx[8];
    #pragma unroll
    for (int j = 0; j < 8; j++) {
      int rp = rg*8 + j;
      float a = 0.f, b = 0.f;
      if (p < 1296) { a = src[(size_t)(k0+2*rp)*1296+p]; b = src[(size_t)(k0+2*rp+1)*1296+p]; }
      rx[j] = cvtpk(a, b);
    }
    const u32* wsrc = wb32 + (size_t)(m0+wrow)*64 + (k0>>1) + wh*8;
    int4 rwA = *(const int4*)wsrc, rwB = *(const int4*)(wsrc+4);
    *(int4*)&Xs[pcol][SWC(pcol,2*rg)*8]   = *(int4*)&rx[0];
    *(int4*)&Xs[pcol][SWC(pcol,2*rg+1)*8] = *(int4*)&rx[4];
    *(int4*)&Ws[wrow][SWC(wrow,2*wh)*8]   = rwA;
    *(int4*)&Ws[wrow][SWC(wrow,2*wh+1)*8] = rwB;
    __syncthreads();
    bf8 af[4], bx[4];
    #pragma unroll
    for (int mt=0;mt<4;mt++) { int r = wm+mt*16+li; af[mt] = *(bf8*)&Ws[r][SWC(r,gr)*8]; }
    #pragma unroll
    for (int pt=0;pt<4;pt++) { int r = wp+pt*16+li; bx[pt] = *(bf8*)&Xs[r][SWC(r,gr)*8]; }
    #pragma unroll
    for (int mt=0;mt<4;mt++)
      #pragma unroll
      for (int pt=0;pt<4;pt++)
        acc[mt][pt] = MFMA(af[mt], bx[pt], acc[mt][pt]);
    __syncthreads();
  }
  u32* out32 = (u32*)out + (size_t)n*128*1296;
  #pragma unroll
  for (int mt=0;mt<4;mt++)
    #pragma unroll
    for (int pt=0;pt<4;pt++) {
      int mb = m0 + wm + mt*16 + gr*4;
      int pp = p0 + wp + pt*16 + li;
      if (pp < 1296) {
        out32[(size_t)(mb>>1)*1296 + pp] = cvtpk(acc[mt][pt][0]+bias[mb], acc[mt][pt][1]+bias[mb+1]);
        out32[(size_t)((mb>>1)+1)*1296 + pp] = cvtpk(acc[mt][pt][2]+bias[mb+2], acc[mt][pt][3]+bias[mb+3]);
      }
    }
}

// ------- fused q/k/v 3x3 convs: tap-major implicit GEMM, dbuf + reg prefetch -------
__global__ __launch_bounds__(256,3) void k_conv3(const u16* __restrict__ xin,
        const u16* __restrict__ wq, const u16* __restrict__ wk, const u16* __restrict__ wv,
        u16* __restrict__ qb, u16* __restrict__ kb, u16* __restrict__ vb) {
  __shared__ u16 Xs[2][128][40];
  __shared__ u16 Ws[2][128][40];
  int tid = threadIdx.x, lane = tid & 63, wid = tid >> 6;
  int li = lane & 15, gr = lane >> 4;
  int kind = blockIdx.y >> 1;            // 0=q(SAME), 1=k, 2=v (VALID)
  int m0 = (blockIdx.y & 1)*128;
  int n = blockIdx.z;
  int P  = (kind == 0) ? 1296 : 1156;
  int WO = (kind == 0) ? 36 : 34;
  int pad = (kind == 0) ? 1 : 0;
  int p0 = blockIdx.x*128;
  if (p0 >= P) return;
  const u16* wt = (kind==0) ? wq : (kind==1) ? wk : wv;
  const u32* src32 = (const u32*)xin + (size_t)n*128*1296;
  const u32* wt32 = (const u32*)wt;
  int pcol = tid & 127, rg = tid >> 7;
  int wrow = tid >> 1, wh = tid & 1;
  int p = p0 + pcol;
  int py = 0, px = 0;
  if (p < P) { py = p / WO; px = p % WO; }
  f4 z = {0.f,0.f,0.f,0.f};
  f4 acc[4][4];
  #pragma unroll
  for (int i=0;i<4;i++) { acc[i][0]=z; acc[i][1]=z; acc[i][2]=z; acc[i][3]=z; }
  int wm = (wid & 1)*64, wp = (wid >> 1)*64;
  u32 rx[8]; int4 rwA, rwB;

  #define LOADIT(tap_, r0_) { \
    int dy = (tap_)/3 - pad, dx = (tap_)%3 - pad; \
    int sy = py + dy, sx = px + dx; \
    bool ok = (p < P) && sy >= 0 && sy < 36 && sx >= 0 && sx < 36; \
    int soff = sy*36 + sx; \
    const u32* xs = src32 + (size_t)(((r0_)>>1) + rg*8)*1296 + soff; \
    _Pragma("unroll") \
    for (int j = 0; j < 8; j++) rx[j] = ok ? xs[(size_t)j*1296] : 0u; \
    const u32* wsrc = wt32 + ((size_t)((tap_)*256 + m0 + wrow))*128 + ((r0_)>>1) + wh*8; \
    rwA = *(const int4*)wsrc; rwB = *(const int4*)(wsrc + 4); }

  LOADIT(0, 0);
  int pb = 0;
  for (int it = 0; it < 72; it++) {
    *(int4*)&Xs[pb][pcol][SWC(pcol,2*rg)*8]   = *(int4*)&rx[0];
    *(int4*)&Xs[pb][pcol][SWC(pcol,2*rg+1)*8] = *(int4*)&rx[4];
    *(int4*)&Ws[pb][wrow][SWC(wrow,2*wh)*8]   = rwA;
    *(int4*)&Ws[pb][wrow][SWC(wrow,2*wh+1)*8] = rwB;
    __syncthreads();
    if (it < 71) {
      int nt = it + 1;
      LOADIT(nt >> 3, (nt & 7)*32);
    }
    bf8 af[4], bx[4];
    #pragma unroll
    for (int mt=0;mt<4;mt++) { int r = wm+mt*16+li; af[mt] = *(bf8*)&Ws[pb][r][SWC(r,gr)*8]; }
    #pragma unroll
    for (int pt=0;pt<4;pt++) { int r = wp+pt*16+li; bx[pt] = *(bf8*)&Xs[pb][r][SWC(r,gr)*8]; }
    #pragma unroll
    for (int mt=0;mt<4;mt++)
      #pragma unroll
      for (int pt=0;pt<4;pt++)
        acc[mt][pt] = MFMA(af[mt], bx[pt], acc[mt][pt]);
    pb ^= 1;
  }
  #undef LOADIT

  if (kind <= 1) {
    u32* dst32 = (u32*)(kind==0 ? qb : kb) + (size_t)n*128*P;
    #pragma unroll
    for (int mt=0;mt<4;mt++)
      #pragma unroll
      for (int pt=0;pt<4;pt++) {
        int mb = m0 + wm + mt*16 + gr*4;
        int pp = p0 + wp + pt*16 + li;
        if (pp < P) {
          dst32[(size_t)(mb>>1)*P + pp] = cvtpk(acc[mt][pt][0], acc[mt][pt][1]);
          dst32[(size_t)((mb>>1)+1)*P + pp] = cvtpk(acc[mt][pt][2], acc[mt][pt][3]);
        }
      }
  } else {
    #pragma unroll
    for (int mt=0;mt<4;mt++)
      #pragma unroll
      for (int pt=0;pt<4;pt++) {
        int pp = p0 + wp + pt*16 + li;
        if (pp < P) {
          #pragma unroll
          for (int j=0;j<4;j++) {
            int m = m0 + wm + mt*16 + gr*4 + j;
            vb[((size_t)n*256 + m)*1156 + pp] = f2b(acc[mt][pt][j]);
          }
        }
      }
  }
}

// ---------------- flash attention, MFMA, online softmax (defer-max) ----------------
__global__ __launch_bounds__(256,2) void k_attn(const u16* __restrict__ qbf,
        const u16* __restrict__ kbf, const u16* __restrict__ vbf, u16* __restrict__ abf) {
  __shared__ u16 Qs[128][40];
  __shared__ u16 Ks[64][40];
  __shared__ u16 Vs[2][32][40];
  __shared__ u16 Ps[4][2][32][40];
  int tid = threadIdx.x, lane = tid & 63, wid = tid >> 6;
  int li = lane & 15, gr = lane >> 4;
  int h = blockIdx.y, n = blockIdx.z;
  int q0 = blockIdx.x*128;
  const u32* Qp32 = (const u32*)qbf + ((size_t)n*128 + h*16)*1296;
  const u32* Kp32 = (const u32*)kbf + ((size_t)n*128 + h*16)*1156;
  const u16* Vp = vbf + ((size_t)n*256 + h*32)*1156;
  #pragma unroll
  for (int j = 0; j < 8; j++) {
    int idx = tid + j*256, qq = idx >> 4, cp = idx & 15;
    int gq = q0 + qq;
    ((u32*)&Qs[qq][0])[cp] = (gq < 1296) ? Qp32[(size_t)cp*1296 + gq] : 0u;
  }
  f4 z = {0.f,0.f,0.f,0.f};
  float mx[2] = {-1e30f, -1e30f}, ls[2] = {0.f, 0.f};
  f4 accO[2][2] = {{z,z},{z,z}};
  int wq = wid*32;
  int kdd = tid >> 2, kq = tid & 3;      // K staging: row kdd, chunk kq
  __syncthreads();
  for (int d0 = 0; d0 < 1156; d0 += 64) {
    {
      u32 kk[4];
      int gd = d0 + kdd;
      #pragma unroll
      for (int i = 0; i < 4; i++)
        kk[i] = (gd < 1156) ? Kp32[(size_t)(kq*4+i)*1156 + gd] : 0u;
      *(int4*)&Ks[kdd][SWC(kdd,kq)*8] = *(int4*)&kk[0];
    }
    #pragma unroll
    for (int j = 0; j < 4; j++) {
      int idx = tid + j*256, half = idx >> 9, rem = idx & 511;
      int cc = rem >> 4, dp = rem & 15;
      int gd = d0 + half*32 + dp*2; u32 v = 0;
      if (gd < 1156) v = *(const u32*)&Vp[(size_t)cc*1156 + gd];
      ((u32*)&Vs[half][cc][0])[dp] = v;
    }
    __syncthreads();
    bf8 ak[4], bq[2];
    #pragma unroll
    for (int dt=0;dt<4;dt++) { int r = dt*16+li; ak[dt] = *(bf8*)&Ks[r][SWC(r,gr)*8]; }
    #pragma unroll
    for (int qt=0;qt<2;qt++) bq[qt] = *(bf8*)&Qs[wq + qt*16 + li][8*gr];
    f4 s[2][4];
    #pragma unroll
    for (int qt=0;qt<2;qt++)
      #pragma unroll
      for (int dt=0;dt<4;dt++)
        s[qt][dt] = MFMA(ak[dt], bq[qt], z);
    bool tail = (d0 + 64 > 1156);
    #pragma unroll
    for (int qt=0;qt<2;qt++) {
      if (tail) {
        #pragma unroll
        for (int dt=0;dt<4;dt++)
          #pragma unroll
          for (int j=0;j<4;j++)
            if (d0 + dt*16 + gr*4 + j >= 1156) s[qt][dt][j] = -1e30f;
      }
      float tm = -1e30f;
      #pragma unroll
      for (int dt=0;dt<4;dt++)
        #pragma unroll
        for (int j=0;j<4;j++) tm = fmaxf(tm, s[qt][dt][j]);
      tm = fmaxf(tm, __shfl_xor(tm, 16));
      tm = fmaxf(tm, __shfl_xor(tm, 32));
      // defer-max (T13): rescale only when some lane's max grew by > 8
      if (__any(tm > mx[qt] + 8.f)) {
        float nm = fmaxf(mx[qt], tm);
        float corr = __expf(mx[qt] - nm);
        mx[qt] = nm;
        ls[qt] *= corr;
        accO[0][qt] *= corr; accO[1][qt] *= corr;
      }
      float rs = 0.f;
      #pragma unroll
      for (int dt=0;dt<4;dt++)
        #pragma unroll
        for (int j=0;j<4;j++) {
          float e = __expf(s[qt][dt][j] - mx[qt]);
          s[qt][dt][j] = e; rs += e;
        }
      rs += __shfl_xor(rs, 16); rs += __shfl_xor(rs, 32);
      ls[qt] += rs;
      #pragma unroll
      for (int dt=0;dt<4;dt++) {
        u32 lo_ = cvtpk(s[qt][dt][0], s[qt][dt][1]);
        u32 hi_ = cvtpk(s[qt][dt][2], s[qt][dt][3]);
        u64 pk = (u64)lo_ | ((u64)hi_ << 32);
        *(u64*)&Ps[wid][dt>>1][qt*16 + li][(dt&1)*16 + gr*4] = pk;
      }
    }
    #pragma unroll
    for (int kt=0;kt<2;kt++) {
      bf8 av0 = *(bf8*)&Vs[kt][li][8*gr];
      bf8 av1 = *(bf8*)&Vs[kt][16 + li][8*gr];
      bf8 bp0 = *(bf8*)&Ps[wid][kt][li][8*gr];
      bf8 bp1 = *(bf8*)&Ps[wid][kt][16 + li][8*gr];
      accO[0][0] = MFMA(av0, bp0, accO[0][0]);
      accO[0][1] = MFMA(av0, bp1, accO[0][1]);
      accO[1][0] = MFMA(av1, bp0, accO[1][0]);
      accO[1][1] = MFMA(av1, bp1, accO[1][1]);
    }
    __syncthreads();
  }
  u32* ab32 = (u32*)abf + (size_t)n*128*1296;
  #pragma unroll
  for (int qt=0;qt<2;qt++) {
    float inv = 1.f / ls[qt];
    #pragma unroll
    for (int mt=0;mt<2;mt++) {
      int cb = h*32 + mt*16 + gr*4;
      int gq = q0 + wq + qt*16 + li;
      if (gq < 1296) {
        ab32[(size_t)(cb>>1)*1296 + gq] = cvtpk(accO[mt][qt][0]*inv, accO[mt][qt][1]*inv);
        ab32[(size_t)((cb>>1)+1)*1296 + gq] = cvtpk(accO[mt][qt][2]*inv, accO[mt][qt][3]*inv);
      }
    }
  }
}

// ---------------- fused gates GEMM (i,g,o; K=512) + LSTM nonlinearity ----------------
__global__ __launch_bounds__(256,2) void k_gates(const u16* __restrict__ abf,
        const u16* __restrict__ xin, const u16* __restrict__ wg,
        const float* __restrict__ b_g, u16* __restrict__ hn) {
  __shared__ u16 Xs[128][40];
  __shared__ u16 Wg[3][64][40];
  int tid = threadIdx.x, lane = tid & 63, wid = tid >> 6;
  int li = lane & 15, gr = lane >> 4;
  int p0 = blockIdx.x*128, m0 = blockIdx.y*64, n = blockIdx.z;
  int pcol = tid & 127, rg = tid >> 7;
  int p = p0 + pcol;
  const u32* wg32 = (const u32*)wg;
  f4 z = {0.f,0.f,0.f,0.f};
  f4 acc[3][2][4];
  #pragma unroll
  for (int g=0;g<3;g++)
    #pragma unroll
    for (int mt=0;mt<2;mt++) { acc[g][mt][0]=z; acc[g][mt][1]=z; acc[g][mt][2]=z; acc[g][mt][3]=z; }
  int wm = (wid & 1)*32, wp = (wid >> 1)*64;
  for (int k0 = 0; k0 < 512; k0 += 32) {
    const u32* src32 = (const u32*)((k0 < 256) ? abf : xin)
        + (size_t)n*128*1296 + (size_t)((k0 & 255)>>1)*1296;
    u32 rx[8];
    #pragma unroll
    for (int j = 0; j < 8; j++) {
      int rp = rg*8 + j;
      rx[j] = (p < 1296) ? src32[(size_t)rp*1296 + p] : 0u;
    }
    *(int4*)&Xs[pcol][SWC(pcol,2*rg)*8]   = *(int4*)&rx[0];
    *(int4*)&Xs[pcol][SWC(pcol,2*rg+1)*8] = *(int4*)&rx[4];
    #pragma unroll
    for (int j = 0; j < 3; j++) {
      int sid = tid + j*256;
      int rid = sid >> 2, q = sid & 3;
      int g = rid >> 6, mm = rid & 63;
      const u32* wsrc = wg32 + (size_t)g*65536 + (size_t)(m0+mm)*256 + (k0>>1) + q*4;
      int4 w4 = *(const int4*)wsrc;
      *(int4*)&Wg[g][mm][SWC(mm,q)*8] = w4;
    }
    __syncthreads();
    bf8 bx[4];
    #pragma unroll
    for (int pt=0;pt<4;pt++) { int r = wp+pt*16+li; bx[pt] = *(bf8*)&Xs[r][SWC(r,gr)*8]; }
    #pragma unroll
    for (int g=0;g<3;g++)
      #pragma unroll
      for (int mt=0;mt<2;mt++) {
        int r = wm+mt*16+li;
        bf8 af = *(bf8*)&Wg[g][r][SWC(r,gr)*8];
        #pragma unroll
        for (int pt=0;pt<4;pt++)
          acc[g][mt][pt] = MFMA(af, bx[pt], acc[g][mt][pt]);
      }
    __syncthreads();
  }
  u32* hn32 = (u32*)hn + (size_t)n*128*1296;
  #pragma unroll
  for (int mt=0;mt<2;mt++)
    #pragma unroll
    for (int pt=0;pt<4;pt++) {
      int rb = m0 + wm + mt*16 + gr*4;
      int pp = p0 + wp + pt*16 + li;
      if (pp < 1296) {
        float hv[4];
        #pragma unroll
        for (int j=0;j<4;j++) {
          float gi = acc[0][mt][pt][j] + b_g[rb+j];
          float gg = acc[1][mt][pt][j] + b_g[512 + rb+j];
          float go = acc[2][mt][pt][j] + b_g[768 + rb+j];
          hv[j] = sigm(go) * tanhf(sigm(gi) * tanhf(gg));
        }
        hn32[(size_t)(rb>>1)*1296 + pp] = cvtpk(hv[0], hv[1]);
        hn32[(size_t)((rb>>1)+1)*1296 + pp] = cvtpk(hv[2], hv[3]);
      }
    }
}

// ---------------- out GEMM: M=256,K=256 over hn (pair-interleaved), out fp32 -------
__global__ __launch_bounds__(256,2) void k_out(const u16* __restrict__ hn,
        const u16* __restrict__ wb, const float* __restrict__ bias,
        float* __restrict__ out) {
  __shared__ u16 Xs[128][40];
  __shared__ u16 Ws[128][40];
  int tid = threadIdx.x, lane = tid & 63, wid = tid >> 6;
  int li = lane & 15, gr = lane >> 4;
  int p0 = blockIdx.x*128, m0 = blockIdx.y*128, n = blockIdx.z;
  int pcol = tid & 127, rg = tid >> 7;
  int wrow = tid >> 1, wh = tid & 1;
  int p = p0 + pcol;
  const u32* src32 = (const u32*)hn + (size_t)n*128*1296;
  const u32* wb32 = (const u32*)wb;
  f4 z = {0.f,0.f,0.f,0.f};
  f4 acc[4][4];
  #pragma unroll
  for (int i=0;i<4;i++) { acc[i][0]=z; acc[i][1]=z; acc[i][2]=z; acc[i][3]=z; }
  int wm = (wid & 1)*64, wp = (wid >> 1)*64;
  for (int k0 = 0; k0 < 256; k0 += 32) {
    u32 rx[8];
    #pragma unroll
    for (int j = 0; j < 8; j++) {
      int rp = rg*8 + j;
      rx[j] = (p < 1296) ? src32[(size_t)((k0>>1) + rp)*1296 + p] : 0u;
    }
    const u32* wsrc = wb32 + (size_t)(m0+wrow)*128 + (k0>>1) + wh*8;
    int4 rwA = *(const int4*)wsrc, rwB = *(const int4*)(wsrc+4);
    *(int4*)&Xs[pcol][SWC(pcol,2*rg)*8]   = *(int4*)&rx[0];
    *(int4*)&Xs[pcol][SWC(pcol,2*rg+1)*8] = *(int4*)&rx[4];
    *(int4*)&Ws[wrow][SWC(wrow,2*wh)*8]   = rwA;
    *(int4*)&Ws[wrow][SWC(wrow,2*wh+1)*8] = rwB;
    __syncthreads();
    bf8 af[4], bx[4];
    #pragma unroll
    for (int mt=0;mt<4;mt++) { int r = wm+mt*16+li; af[mt] = *(bf8*)&Ws[r][SWC(r,gr)*8]; }
    #pragma unroll
    for (int pt=0;pt<4;pt++) { int r = wp+pt*16+li; bx[pt] = *(bf8*)&Xs[r][SWC(r,gr)*8]; }
    #pragma unroll
    for (int mt=0;mt<4;mt++)
      #pragma unroll
      for (int pt=0;pt<4;pt++)
        acc[mt][pt] = MFMA(af[mt], bx[pt], acc[mt][pt]);
    __syncthreads();
  }
  #pragma unroll
  for (int mt=0;mt<4;mt++)
    #pragma unroll
    for (int pt=0;pt<4;pt++)
      #pragma unroll
      for (int j=0;j<4;j++) {
        int m = m0 + wm + mt*16 + gr*4 + j;
        int pp = p0 + wp + pt*16 + li;
        if (pp < 1296) out[((size_t)n*256 + m)*1296 + pp] = acc[mt][pt][j] + bias[m];
      }
}

extern "C" void kernel_launch(void* const* d_in, const int* in_sizes, int n_in,
                              void* d_out, int out_size, void* d_ws, size_t ws_size,
                              hipStream_t stream) {
  const float* x     = (const float*)d_in[0];
  const float* w_in  = (const float*)d_in[1];
  const float* b_in  = (const float*)d_in[2];
  const float* w_qx  = (const float*)d_in[3];
  const float* w_kx  = (const float*)d_in[5];
  const float* w_vx  = (const float*)d_in[7];
  const float* w_ga  = (const float*)d_in[9];
  const float* b_g   = (const float*)d_in[10];
  const float* w_gx  = (const float*)d_in[11];
  const float* w_out = (const float*)d_in[13];
  const float* b_out = (const float*)d_in[14];
  float* out = (float*)d_out;

  u16* ws = (u16*)d_ws;
  size_t o = 0;
  u16* xin_bf = ws + o; o += 2654208;
  u16* qbuf   = ws + o; o += 2654208;
  u16* kbuf   = ws + o; o += 2367488;
  u16* vbuf   = ws + o; o += 2367488;
  u16* abuf   = ws + o; o += 2654208;
  u16* hnb    = ws + o; o += 2654208;
  u16* wqT    = ws + o; o += 589824;
  u16* wkT    = ws + o; o += 589824;
  u16* wvT    = ws + o; o += 589824;
  u16* wgT    = ws + o; o += 393216;
  u16* winb   = ws + o; o += 32768;
  u16* woutb  = ws + o; o += 65536;

  k_cvt<<<128, 256, 0, stream>>>(w_in, winb, 32768);
  k_cvt<<<256, 256, 0, stream>>>(w_out, woutb, 65536);
  k_wt3<<<dim3(2304,3), 256, 0, stream>>>(w_qx, w_kx, w_vx, wqT, wkT, wvT);
  k_wtg<<<1536, 256, 0, stream>>>(w_ga, w_gx, wgT);

  k_xin  <<<dim3(11,2,8), 256, 0, stream>>>(x, winb, b_in, xin_bf);
  k_conv3<<<dim3(11,6,8), 256, 0, stream>>>(xin_bf, wqT, wkT, wvT, qbuf, kbuf, vbuf);
  k_attn <<<dim3(11,8,8), 256, 0, stream>>>(qbuf, kbuf, vbuf, abuf);
  k_gates<<<dim3(11,4,8), 256, 0, stream>>>(abuf, xin_bf, wgT, b_g, hnb);
  k_out  <<<dim3(11,2,8), 256, 0, stream>>>(hnb, woutb, b_out, out);
}